// Round 17
// baseline (119.505 us; speedup 1.0000x reference)
//
#include <hip/hip_runtime.h>

typedef __attribute__((ext_vector_type(8))) short short8;
typedef __attribute__((ext_vector_type(4))) short short4v;
typedef __attribute__((ext_vector_type(4))) float f32x4;

__device__ inline unsigned short f2bf(float f) {
  union { float f; unsigned int u; } v; v.f = f;
  unsigned int r = v.u + 0x7FFFu + ((v.u >> 16) & 1u);
  return (unsigned short)(r >> 16);
}

__device__ inline unsigned cvtpk_bf16(float lo, float hi) {
  unsigned r;
  asm("v_cvt_pk_bf16_f32 %0, %1, %2" : "=v"(r) : "v"(lo), "v"(hi));
  return r;
}

__device__ inline void gload_lds16(const void* g, void* l) {
  __builtin_amdgcn_global_load_lds(
      (const __attribute__((address_space(1))) unsigned int*)g,
      (__attribute__((address_space(3))) unsigned int*)l, 16, 0, 0);
}

#define LGKM(n) asm volatile("s_waitcnt lgkmcnt(" #n ")" ::: "memory")

// ---------------- fused prep: x->bf16 | 4x weight transpose | bias pack ----------------

__global__ __launch_bounds__(256) void prep(
    const float* __restrict__ x,
    const float* __restrict__ wq, const float* __restrict__ wk,
    const float* __restrict__ wv, const float* __restrict__ wo,
    const float* __restrict__ bq, const float* __restrict__ bk,
    const float* __restrict__ bv,
    unsigned short* __restrict__ xb, unsigned short* __restrict__ wqkvT,
    unsigned short* __restrict__ woT, float* __restrict__ bqkv) {
  const int bid = blockIdx.x;
  if (bid < 4096) {
    const int i = bid * 256 + threadIdx.x;
    float4 v = ((const float4*)x)[i];
    ushort4 o;
    o.x = f2bf(v.x); o.y = f2bf(v.y); o.z = f2bf(v.z); o.w = f2bf(v.w);
    ((ushort4*)xb)[i] = o;
  } else if (bid < 8192) {
    const int u = bid - 4096;
    const int z = u >> 10, rem = u & 1023;
    const float* w = (z == 0) ? wq : (z == 1) ? wk : (z == 2) ? wv : wo;
    unsigned short* dst = (z < 3) ? (wqkvT + (size_t)z * 1024 * 1024) : woT;
    const float scale = (z == 0) ? 0.18033688011f : 1.0f;  // 0.125*log2(e)
    __shared__ float t[32][33];
    const int k0 = (rem & 31) * 32;
    const int n0 = (rem >> 5) * 32;
    const int tx = threadIdx.x & 31, ty = threadIdx.x >> 5;
#pragma unroll
    for (int i = 0; i < 32; i += 8)
      t[ty + i][tx] = w[(size_t)(k0 + ty + i) * 1024 + n0 + tx];
    __syncthreads();
#pragma unroll
    for (int i = 0; i < 32; i += 8)
      dst[(size_t)(n0 + ty + i) * 1024 + k0 + tx] = f2bf(t[tx][ty + i] * scale);
  } else {
    const int i = (bid - 8192) * 256 + threadIdx.x;
    float v;
    if (i < 1024) v = bq[i] * 0.18033688011f;
    else if (i < 2048) v = bk[i - 1024];
    else v = bv[i - 2048];
    bqkv[i] = v;
  }
}

// ---------------- GEMM 64x64 tile (O-projection; double-buffered) ----------------

__global__ __launch_bounds__(256) void gemm_bt64b(
    const unsigned short* __restrict__ A, const unsigned short* __restrict__ Bt,
    const float* __restrict__ bias, float* __restrict__ C, int K, int ldc) {
  __shared__ unsigned short As[2][64 * 32];
  __shared__ unsigned short Bs[2][64 * 32];
  const int tid = threadIdx.x;
  const int lane = tid & 63;
  const int wave = tid >> 6;
  const int wm = (wave >> 1) * 32;
  const int wn = (wave & 1) * 32;
  const long bm = (long)blockIdx.x * 64;
  const long bn = (long)blockIdx.y * 64;

  const int sr = tid >> 2;
  const int sc = (tid & 3) * 8;
  const unsigned short* Ag0 = A + (bm + sr) * (long)K + sc;
  const unsigned short* Bg0 = Bt + (bn + sr) * (long)K + sc;

  auto stage = [&](int buf) {
    gload_lds16(Ag0, &As[buf][tid * 8]);
    gload_lds16(Bg0, &Bs[buf][tid * 8]);
    Ag0 += 32; Bg0 += 32;
  };

  f32x4 acc[2][2] = {};

  const int fr = lane & 15;
  const int fk = (lane >> 4) * 8;

  stage(0);
  __syncthreads();

  const int nkt = K / 32;
  for (int kt = 0; kt < nkt; kt++) {
    const int cur = kt & 1;
    if (kt + 1 < nkt) stage(cur ^ 1);  // prefetch; latency hides under compute
    short8 af[2], bfv[2];
#pragma unroll
    for (int i = 0; i < 2; i++) af[i] = *(const short8*)&As[cur][(wm + i * 16 + fr) * 32 + fk];
#pragma unroll
    for (int j = 0; j < 2; j++) bfv[j] = *(const short8*)&Bs[cur][(wn + j * 16 + fr) * 32 + fk];
#pragma unroll
    for (int i = 0; i < 2; i++)
#pragma unroll
      for (int j = 0; j < 2; j++)
        acc[i][j] = __builtin_amdgcn_mfma_f32_16x16x32_bf16(af[i], bfv[j], acc[i][j], 0, 0, 0);
    __syncthreads();  // next tile staged + all reads of cur done
  }

  const int crow = (lane >> 4) * 4;
  const int ccol = lane & 15;
#pragma unroll
  for (int j = 0; j < 2; j++) {
    const long col = bn + wn + j * 16 + ccol;
    const float bv = bias[col];
#pragma unroll
    for (int i = 0; i < 2; i++)
#pragma unroll
      for (int r = 0; r < 4; r++) {
        const long row = bm + wm + i * 16 + crow + r;
        C[row * ldc + col] = acc[i][j][r] + bv;
      }
  }
}

// ---------------- GEMM 256^2, BK=64, 8 waves, 8-phase counted-vmcnt ----------------
// r16 change: A-fragment reads issued ONE PHASE EARLY with counted lgkm —
// g0 issues B(8)+A0(4)+A1(4), waits lgkm(4) (A1 in flight); g1/g2 issue A2/A3,
// wait lgkm(4); g3 waits lgkm(0). Hides ~120cy ds_read latency of A1..A3 under
// the previous phase's MFMAs. Safety: every read of a region is lgkm-complete
// before any stage targets that region (stages touch the OTHER buffer's A, and
// same-buffer B only after g0's wait covered all B reads) — same invariant as
// the original schedule.

__global__ __launch_bounds__(512, 2) void gemm256(
    const unsigned short* __restrict__ A, const unsigned short* __restrict__ Bt,
    const float* __restrict__ bias, unsigned short* __restrict__ C, int ldc) {
  constexpr int K = 1024;
  __shared__ unsigned short Sab[2][2][16384];  // [buf][0=A,1=B][256*64]
  const int tid = threadIdx.x;
  const int lane = tid & 63;
  const int w = tid >> 6;
  const int wr = w >> 2, wc = w & 3;
  const long bm = (long)blockIdx.x * 256;
  const long bn = (long)blockIdx.y * 256;
  const int fr = lane & 15, fg = lane >> 4;

  const int srow = tid >> 3;  // 0..63
  const int kch = tid & 7;

  auto stage = [&](int o, int buf, int tk, int h) {
#pragma unroll
    for (int l = 0; l < 2; ++l) {
      const int rih = l * 64 + srow;
      const unsigned short* src = (o ? Bt : A) +
          ((o ? bn : bm) + h * 128 + rih) * (long)K + tk * 64 + ((kch ^ (rih & 7)) * 8);
      gload_lds16(src, &Sab[buf][o][h * 8192 + (l * 512 + tid) * 8]);
    }
  };

  f32x4 acc[8][4] = {};

  stage(0, 0, 0, 0); stage(0, 0, 0, 1);
  stage(1, 0, 0, 0); stage(1, 0, 0, 1);
  stage(1, 1, 1, 0); stage(1, 1, 1, 1);
  asm volatile("s_waitcnt vmcnt(4)" ::: "memory");
  __builtin_amdgcn_s_barrier();

  for (int it = 0; it < 8; ++it) {
    const int T = 2 * it;
    const int tkA = (T + 2 < 15) ? T + 2 : 15;
    const int tkB3 = (T + 3 < 15) ? T + 3 : 15;
#pragma unroll
    for (int half = 0; half < 2; ++half) {
      const int b = half;
      short8 bfr[4][2];
      short8 afr[4][2][2];
#pragma unroll
      for (int g = 0; g < 4; ++g) {
        // ds reads: g0 issues B + A-phase0 + A-phase1; g1/g2 issue A-phase g+1
        if (g == 0) {
#pragma unroll
          for (int nj = 0; nj < 4; ++nj)
#pragma unroll
            for (int kc = 0; kc < 2; ++kc) {
              const int r = wc * 64 + nj * 16 + fr;
              bfr[nj][kc] = *(const short8*)&Sab[b][1][r * 64 + ((kc * 4 + fg) ^ (r & 7)) * 8];
            }
#pragma unroll
          for (int ph = 0; ph < 2; ++ph)
#pragma unroll
            for (int mil = 0; mil < 2; ++mil)
#pragma unroll
              for (int kc = 0; kc < 2; ++kc) {
                const int r = wr * 128 + (2 * ph + mil) * 16 + fr;
                afr[ph][mil][kc] = *(const short8*)&Sab[b][0][r * 64 + ((kc * 4 + fg) ^ (r & 7)) * 8];
              }
        } else if (g < 3) {
#pragma unroll
          for (int mil = 0; mil < 2; ++mil)
#pragma unroll
            for (int kc = 0; kc < 2; ++kc) {
              const int r = wr * 128 + (2 * (g + 1) + mil) * 16 + fr;
              afr[g + 1][mil][kc] = *(const short8*)&Sab[b][0][r * 64 + ((kc * 4 + fg) ^ (r & 7)) * 8];
            }
        }
        // stage per schedule
        if (half == 0) {
          if (g == 0)      { stage(0, 1, T + 1, 0); stage(0, 1, T + 1, 1); }
          else if (g == 1) { stage(1, 0, tkA, 0); }
          else if (g == 2) { stage(1, 0, tkA, 1); }
        } else {
          if (g == 0)      { stage(0, 0, tkA, 0); stage(0, 0, tkA, 1); }
          else if (g == 1) { stage(1, 1, tkB3, 0); }
          else if (g == 2) { stage(1, 1, tkB3, 1); }
        }
        __builtin_amdgcn_s_barrier();
        if (g < 3) { LGKM(4); } else { LGKM(0); }
        __builtin_amdgcn_sched_barrier(0);
        __builtin_amdgcn_s_setprio(1);
#pragma unroll
        for (int mil = 0; mil < 2; ++mil)
#pragma unroll
          for (int nj = 0; nj < 4; ++nj)
#pragma unroll
            for (int kc = 0; kc < 2; ++kc)
              acc[2 * g + mil][nj] = __builtin_amdgcn_mfma_f32_16x16x32_bf16(
                  afr[g][mil][kc], bfr[nj][kc], acc[2 * g + mil][nj], 0, 0, 0);
        __builtin_amdgcn_s_setprio(0);
        if (g == 3) asm volatile("s_waitcnt vmcnt(4)" ::: "memory");
        __builtin_amdgcn_s_barrier();
      }
    }
  }

  const int crow = fg * 4;
  const int ccol = fr;
#pragma unroll
  for (int nj = 0; nj < 4; ++nj) {
    const long col = bn + wc * 64 + nj * 16 + ccol;
    const float bv = bias[col];
#pragma unroll
    for (int mi = 0; mi < 8; ++mi)
#pragma unroll
      for (int r = 0; r < 4; ++r) {
        const long row = bm + wr * 128 + mi * 16 + crow + r;
        C[row * ldc + col] = f2bf(acc[mi][nj][r] + bv);
      }
  }
}

// ---------------- flash attention (v15: r13 + hoisted sum-reduce; unchanged) ----------------

#define KSWZ(row) (((row) & 3) | ((((row) >> 3) & 1) << 2))
#define TRRD(d, o) asm volatile("ds_read_b64_tr_b16 %0, %1 offset:" o \
                                : "=v"(d) : "v"(vtr) : "memory")

__global__ __launch_bounds__(512, 2) void attn_fwd(
    const unsigned short* __restrict__ qkv, unsigned short* __restrict__ out) {
  __shared__ unsigned short S[6 * 4096];  // Ks = S[0..3 bufs), Vs = S[3 bufs..6 bufs)
  __shared__ float msArr[512];
  unsigned short* Ks = &S[0];
  unsigned short* Vs = &S[3 * 4096];
  const int tid = threadIdx.x;
  const int lane = tid & 63;
  const int w = tid >> 6;
  const int qh = w >> 1, kh = w & 1;  // qh 0..3

  const int xcd = blockIdx.x & 7, slot = blockIdx.x >> 3;  // slot 0..63
  const int pair = xcd * 4 + (slot >> 4);                  // 0..31
  const int qtile = slot & 15;
  const int h = pair & 15, b = pair >> 4;
  const long rowbase = (long)b * 2048;
  const int hq = h * 64;
  const int fr = lane & 15;
  const int fg = lane >> 4;
  const int fk = fg * 8;
  const int q0 = qtile * 128 + qh * 32;

  short8 qf[2][2];
#pragma unroll
  for (int qi = 0; qi < 2; qi++) {
    const long qr = rowbase + q0 + qi * 16 + fr;
    qf[qi][0] = *(const short8*)&qkv[qr * 3072 + hq + fk];
    qf[qi][1] = *(const short8*)&qkv[qr * 3072 + hq + 32 + fk];
  }

  const int kr = tid >> 3;  // 0..63
  const unsigned short* Kg0 = &qkv[(rowbase + kr) * 3072 + 1024 + hq + (((tid & 7) ^ KSWZ(kr)) * 8)];
  const int vkv = ((tid >> 1) & 3) + ((tid >> 5) & 1) * 4 + ((tid >> 3) & 3) * 8 + ((tid >> 8) & 1) * 32;
  const int vd0 = (tid & 1) * 8 + ((tid >> 6) & 3) * 16;
  const unsigned short* Vg0 = &qkv[(rowbase + vkv) * 3072 + 2048 + hq + vd0];

  auto stage = [&](int tk, int buf) {
    const long off = (long)tk * 64 * 3072;
    gload_lds16(Kg0 + off, &Ks[buf * 4096 + tid * 8]);
    gload_lds16(Vg0 + off, &Vs[buf * 4096 + tid * 8]);
  };

  f32x4 o[2][4] = {};
  float m_[2] = {-1e30f, -1e30f};
  float s_[2] = {0.f, 0.f};  // per-lane partials; reduced once after the loop

  const int krowbase = kh * 32 + (fr >> 2) * 8 + (fr & 3);  // + n*4

  stage(0, 0);
  stage(1, 1);
  asm volatile("s_waitcnt vmcnt(2)" ::: "memory");
  __builtin_amdgcn_s_barrier();

  int cur = 0;

  for (int t = 0; t < 32; t++) {
    {
      int stg = cur + 2; if (stg >= 3) stg -= 3;
      const int tk = (t + 2 < 31) ? t + 2 : 31;
      stage(tk, stg);
    }

    f32x4 sa[2][2];
    __builtin_amdgcn_s_setprio(1);
#pragma unroll
    for (int n = 0; n < 2; n++) {
      const int row = krowbase + n * 4;
      const short8 kf0 = *(const short8*)&Ks[cur * 4096 + ((row * 64 + fk) ^ (KSWZ(row) << 3))];
      const short8 kf1 = *(const short8*)&Ks[cur * 4096 + ((row * 64 + 32 + fk) ^ (KSWZ(row) << 3))];
#pragma unroll
      for (int qi = 0; qi < 2; qi++) {
        f32x4 z = {0.f, 0.f, 0.f, 0.f};
        z = __builtin_amdgcn_mfma_f32_16x16x32_bf16(kf0, qf[qi][0], z, 0, 0, 0);
        sa[qi][n] = __builtin_amdgcn_mfma_f32_16x16x32_bf16(kf1, qf[qi][1], z, 0, 0, 0);
      }
    }
    __builtin_amdgcn_s_setprio(0);

    float lmax[2];
#pragma unroll
    for (int qi = 0; qi < 2; qi++)
      lmax[qi] = fmaxf(fmaxf(fmaxf(sa[qi][0][0], sa[qi][0][1]), fmaxf(sa[qi][0][2], sa[qi][0][3])),
                       fmaxf(fmaxf(sa[qi][1][0], sa[qi][1][1]), fmaxf(sa[qi][1][2], sa[qi][1][3])));
    if (__any(fmaxf(lmax[0] - m_[0], lmax[1] - m_[1]) > 8.f)) {
#pragma unroll
      for (int qi = 0; qi < 2; qi++) {
        float mx = lmax[qi];
        mx = fmaxf(mx, __shfl_xor(mx, 16));
        mx = fmaxf(mx, __shfl_xor(mx, 32));
        const float nm = fmaxf(m_[qi], mx);
        const float fac = __builtin_amdgcn_exp2f(m_[qi] - nm);
        m_[qi] = nm;
        s_[qi] *= fac;
        float facp[4];
#pragma unroll
        for (int r = 0; r < 4; r++) facp[r] = __shfl(fac, fg * 4 + r);
#pragma unroll
        for (int dj = 0; dj < 4; dj++)
#pragma unroll
          for (int r = 0; r < 4; r++) o[qi][dj][r] *= facp[r];
      }
    }

    short8 pa[2];
#pragma unroll
    for (int qi = 0; qi < 2; qi++) {
      float p[8];
#pragma unroll
      for (int n = 0; n < 2; n++)
#pragma unroll
        for (int r = 0; r < 4; r++)
          p[n * 4 + r] = __builtin_amdgcn_exp2f(sa[qi][n][r] - m_[qi]);
      s_[qi] += ((p[0] + p[1]) + (p[2] + p[3])) + ((p[4] + p[5]) + (p[6] + p[7]));
      union { unsigned u[4]; short8 v; } pk;
      pk.u[0] = cvtpk_bf16(p[0], p[1]);
      pk.u[1] = cvtpk_bf16(p[2], p[3]);
      pk.u[2] = cvtpk_bf16(p[4], p[5]);
      pk.u[3] = cvtpk_bf16(p[6], p[7]);
      pa[qi] = pk.v;
    }

    const __attribute__((address_space(3))) unsigned short* vtr =
        (const __attribute__((address_space(3))) unsigned short*)&Vs[0] +
        cur * 4096 + kh * 2048 + lane * 4;
    short4v v0[4], v1[4];
    TRRD(v0[0], "0");    TRRD(v1[0], "512");
    TRRD(v0[1], "1024"); TRRD(v1[1], "1536");
    TRRD(v0[2], "2048"); TRRD(v1[2], "2560");
    TRRD(v0[3], "3072"); TRRD(v1[3], "3584");

    __builtin_amdgcn_s_setprio(1);
    LGKM(6); __builtin_amdgcn_sched_barrier(0);
    {
      short8 vf = __builtin_shufflevector(v0[0], v1[0], 0, 1, 2, 3, 4, 5, 6, 7);
      o[0][0] = __builtin_amdgcn_mfma_f32_16x16x32_bf16(pa[0], vf, o[0][0], 0, 0, 0);
      o[1][0] = __builtin_amdgcn_mfma_f32_16x16x32_bf16(pa[1], vf, o[1][0], 0, 0, 0);
    }
    LGKM(4); __builtin_amdgcn_sched_barrier(0);
    {
      short8 vf = __builtin_shufflevector(v0[1], v1[1], 0, 1, 2, 3, 4, 5, 6, 7);
      o[0][1] = __builtin_amdgcn_mfma_f32_16x16x32_bf16(pa[0], vf, o[0][1], 0, 0, 0);
      o[1][1] = __builtin_amdgcn_mfma_f32_16x16x32_bf16(pa[1], vf, o[1][1], 0, 0, 0);
    }
    LGKM(2); __builtin_amdgcn_sched_barrier(0);
    {
      short8 vf = __builtin_shufflevector(v0[2], v1[2], 0, 1, 2, 3, 4, 5, 6, 7);
      o[0][2] = __builtin_amdgcn_mfma_f32_16x16x32_bf16(pa[0], vf, o[0][2], 0, 0, 0);
      o[1][2] = __builtin_amdgcn_mfma_f32_16x16x32_bf16(pa[1], vf, o[1][2], 0, 0, 0);
    }
    LGKM(0); __builtin_amdgcn_sched_barrier(0);
    {
      short8 vf = __builtin_shufflevector(v0[3], v1[3], 0, 1, 2, 3, 4, 5, 6, 7);
      o[0][3] = __builtin_amdgcn_mfma_f32_16x16x32_bf16(pa[0], vf, o[0][3], 0, 0, 0);
      o[1][3] = __builtin_amdgcn_mfma_f32_16x16x32_bf16(pa[1], vf, o[1][3], 0, 0, 0);
    }
    __builtin_amdgcn_s_setprio(0);

    asm volatile("s_waitcnt vmcnt(2) lgkmcnt(0)" ::: "memory");
    __builtin_amdgcn_s_barrier();

    cur = (cur == 2) ? 0 : cur + 1;
  }

#pragma unroll
  for (int qi = 0; qi < 2; qi++) {
    s_[qi] += __shfl_xor(s_[qi], 16);
    s_[qi] += __shfl_xor(s_[qi], 32);
  }

  float* mo = (float*)&S[0];
  __syncthreads();
  if (kh == 1) {
#pragma unroll
    for (int qi = 0; qi < 2; qi++)
#pragma unroll
      for (int dj = 0; dj < 4; dj++)
#pragma unroll
        for (int r = 0; r < 4; r++)
          mo[(qh * 32 + qi * 16 + dj * 4 + r) * 64 + lane] = o[qi][dj][r];
  }
  if (fg == 0) {
#pragma unroll
    for (int qi = 0; qi < 2; qi++) {
      msArr[(((kh * 4 + qh) * 2 + qi) * 2 + 0) * 16 + fr] = m_[qi];
      msArr[(((kh * 4 + qh) * 2 + qi) * 2 + 1) * 16 + fr] = s_[qi];
    }
  }
  __syncthreads();
  if (kh == 0) {
#pragma unroll
    for (int qi = 0; qi < 2; qi++) {
      float f0[4], f1[4], rs[4];
#pragma unroll
      for (int r = 0; r < 4; r++) {
        const int qp = fg * 4 + r;
        const float m0 = msArr[(((0 * 4 + qh) * 2 + qi) * 2 + 0) * 16 + qp];
        const float s0 = msArr[(((0 * 4 + qh) * 2 + qi) * 2 + 1) * 16 + qp];
        const float m1 = msArr[(((1 * 4 + qh) * 2 + qi) * 2 + 0) * 16 + qp];
        const float s1 = msArr[(((1 * 4 + qh) * 2 + qi) * 2 + 1) * 16 + qp];
        const float mstar = fmaxf(m0, m1);
        f0[r] = __builtin_amdgcn_exp2f(m0 - mstar);
        f1[r] = __builtin_amdgcn_exp2f(m1 - mstar);
        rs[r] = __builtin_amdgcn_rcpf(s0 * f0[r] + s1 * f1[r]);
      }
#pragma unroll
      for (int dj = 0; dj < 4; dj++)
#pragma unroll
        for (int r = 0; r < 4; r++) {
          const float o1 = mo[(qh * 32 + qi * 16 + dj * 4 + r) * 64 + lane];
          const float val = (o[qi][dj][r] * f0[r] + o1 * f1[r]) * rs[r];
          const long row = rowbase + q0 + qi * 16 + fg * 4 + r;
          out[row * 1024 + hq + dj * 16 + fr] = f2bf(val);
        }
    }
  }
}

// ---------------- host ----------------

extern "C" void kernel_launch(void* const* d_in, const int* in_sizes, int n_in,
                              void* d_out, int out_size, void* d_ws, size_t ws_size,
                              hipStream_t stream) {
  const float* x  = (const float*)d_in[0];
  const float* wq = (const float*)d_in[1];
  const float* bq = (const float*)d_in[2];
  const float* wk = (const float*)d_in[3];
  const float* bk = (const float*)d_in[4];
  const float* wv = (const float*)d_in[5];
  const float* bv = (const float*)d_in[6];
  const float* wo = (const float*)d_in[7];
  const float* bo = (const float*)d_in[8];

  char* ws = (char*)d_ws;
  unsigned short* xb    = (unsigned short*)(ws);                       // 8 MB  [4096][1024]
  unsigned short* wqkvT = (unsigned short*)(ws + (8ull  << 20));       // 6 MB  [3072][1024]
  unsigned short* woT   = (unsigned short*)(ws + (14ull << 20));       // 2 MB  [1024][1024]
  float*          bqkv  = (float*)         (ws + (16ull << 20));       // 12 KB [3072]
  unsigned short* qkv   = (unsigned short*)(ws + (17ull << 20));       // 24 MB [4096][3072]
  unsigned short* attn  = (unsigned short*)(ws + (41ull << 20));       // 8 MB  [4096][1024]

  prep<<<8204, 256, 0, stream>>>(x, wq, wk, wv, wo, bq, bk, bv, xb, wqkvT, woT, bqkv);

  gemm256<<<dim3(16, 12), 512, 0, stream>>>(xb, wqkvT, bqkv, qkv, 3072);

  attn_fwd<<<512, 512, 0, stream>>>(qkv, attn);

  gemm_bt64b<<<dim3(64, 16), 256, 0, stream>>>(attn, woT, bo, (float*)d_out, 1024, 1024);
}

// Round 18
// 113.019 us; speedup vs baseline: 1.0574x; 1.0574x over previous
//
#include <hip/hip_runtime.h>

typedef __attribute__((ext_vector_type(8))) short short8;
typedef __attribute__((ext_vector_type(4))) short short4v;
typedef __attribute__((ext_vector_type(4))) float f32x4;

__device__ inline unsigned short f2bf(float f) {
  union { float f; unsigned int u; } v; v.f = f;
  unsigned int r = v.u + 0x7FFFu + ((v.u >> 16) & 1u);
  return (unsigned short)(r >> 16);
}

__device__ inline unsigned cvtpk_bf16(float lo, float hi) {
  unsigned r;
  asm("v_cvt_pk_bf16_f32 %0, %1, %2" : "=v"(r) : "v"(lo), "v"(hi));
  return r;
}

__device__ inline void gload_lds16(const void* g, void* l) {
  __builtin_amdgcn_global_load_lds(
      (const __attribute__((address_space(1))) unsigned int*)g,
      (__attribute__((address_space(3))) unsigned int*)l, 16, 0, 0);
}

// ---------------- fused prep: x->bf16 | 4x weight transpose | bias pack ----------------

__global__ __launch_bounds__(256) void prep(
    const float* __restrict__ x,
    const float* __restrict__ wq, const float* __restrict__ wk,
    const float* __restrict__ wv, const float* __restrict__ wo,
    const float* __restrict__ bq, const float* __restrict__ bk,
    const float* __restrict__ bv,
    unsigned short* __restrict__ xb, unsigned short* __restrict__ wqkvT,
    unsigned short* __restrict__ woT, float* __restrict__ bqkv) {
  const int bid = blockIdx.x;
  if (bid < 4096) {
    const int i = bid * 256 + threadIdx.x;
    float4 v = ((const float4*)x)[i];
    ushort4 o;
    o.x = f2bf(v.x); o.y = f2bf(v.y); o.z = f2bf(v.z); o.w = f2bf(v.w);
    ((ushort4*)xb)[i] = o;
  } else if (bid < 8192) {
    const int u = bid - 4096;
    const int z = u >> 10, rem = u & 1023;
    const float* w = (z == 0) ? wq : (z == 1) ? wk : (z == 2) ? wv : wo;
    unsigned short* dst = (z < 3) ? (wqkvT + (size_t)z * 1024 * 1024) : woT;
    const float scale = (z == 0) ? 0.18033688011f : 1.0f;  // 0.125*log2(e)
    __shared__ float t[32][33];
    const int k0 = (rem & 31) * 32;
    const int n0 = (rem >> 5) * 32;
    const int tx = threadIdx.x & 31, ty = threadIdx.x >> 5;
#pragma unroll
    for (int i = 0; i < 32; i += 8)
      t[ty + i][tx] = w[(size_t)(k0 + ty + i) * 1024 + n0 + tx];
    __syncthreads();
#pragma unroll
    for (int i = 0; i < 32; i += 8)
      dst[(size_t)(n0 + ty + i) * 1024 + k0 + tx] = f2bf(t[tx][ty + i] * scale);
  } else {
    const int i = (bid - 8192) * 256 + threadIdx.x;
    float v;
    if (i < 1024) v = bq[i] * 0.18033688011f;
    else if (i < 2048) v = bk[i - 1024];
    else v = bv[i - 2048];
    bqkv[i] = v;
  }
}

// ---------------- GEMM 64x64 tile (O-projection; 4 blocks/CU) ----------------

__global__ __launch_bounds__(256) void gemm_bt64b(
    const unsigned short* __restrict__ A, const unsigned short* __restrict__ Bt,
    const float* __restrict__ bias, float* __restrict__ C, int K, int ldc) {
  __shared__ unsigned short As[64 * 32];
  __shared__ unsigned short Bs[64 * 32];
  const int tid = threadIdx.x;
  const int lane = tid & 63;
  const int wave = tid >> 6;
  const int wm = (wave >> 1) * 32;
  const int wn = (wave & 1) * 32;
  const long bm = (long)blockIdx.x * 64;
  const long bn = (long)blockIdx.y * 64;

  const int sr = tid >> 2;
  const int sc = (tid & 3) * 8;
  const unsigned short* Ag0 = A + (bm + sr) * (long)K + sc;
  const unsigned short* Bg0 = Bt + (bn + sr) * (long)K + sc;
  unsigned short* As0 = &As[tid * 8];
  unsigned short* Bs0 = &Bs[tid * 8];

  f32x4 acc[2][2] = {};

  const int fr = lane & 15;
  const int fk = (lane >> 4) * 8;

  for (int kt = 0; kt < K; kt += 32) {
    gload_lds16(Ag0, As0);
    gload_lds16(Bg0, Bs0);
    Ag0 += 32; Bg0 += 32;
    __syncthreads();
    short8 af[2], bfv[2];
#pragma unroll
    for (int i = 0; i < 2; i++) af[i] = *(const short8*)&As[(wm + i * 16 + fr) * 32 + fk];
#pragma unroll
    for (int j = 0; j < 2; j++) bfv[j] = *(const short8*)&Bs[(wn + j * 16 + fr) * 32 + fk];
#pragma unroll
    for (int i = 0; i < 2; i++)
#pragma unroll
      for (int j = 0; j < 2; j++)
        acc[i][j] = __builtin_amdgcn_mfma_f32_16x16x32_bf16(af[i], bfv[j], acc[i][j], 0, 0, 0);
    __syncthreads();
  }

  const int crow = (lane >> 4) * 4;
  const int ccol = lane & 15;
#pragma unroll
  for (int j = 0; j < 2; j++) {
    const long col = bn + wn + j * 16 + ccol;
    const float bv = bias[col];
#pragma unroll
    for (int i = 0; i < 2; i++)
#pragma unroll
      for (int r = 0; r < 4; r++) {
        const long row = bm + wm + i * 16 + crow + r;
        C[row * ldc + col] = acc[i][j][r] + bv;
      }
  }
}

// ---------------- GEMM 256^2, BK=64, 8 waves, 8-phase counted-vmcnt ----------------

__global__ __launch_bounds__(512, 2) void gemm256(
    const unsigned short* __restrict__ A, const unsigned short* __restrict__ Bt,
    const float* __restrict__ bias, unsigned short* __restrict__ C, int ldc) {
  constexpr int K = 1024;
  __shared__ unsigned short Sab[2][2][16384];  // [buf][0=A,1=B][256*64]
  const int tid = threadIdx.x;
  const int lane = tid & 63;
  const int w = tid >> 6;
  const int wr = w >> 2, wc = w & 3;
  const long bm = (long)blockIdx.x * 256;
  const long bn = (long)blockIdx.y * 256;
  const int fr = lane & 15, fg = lane >> 4;

  const int srow = tid >> 3;  // 0..63
  const int kch = tid & 7;

  auto stage = [&](int o, int buf, int tk, int h) {
#pragma unroll
    for (int l = 0; l < 2; ++l) {
      const int rih = l * 64 + srow;
      const unsigned short* src = (o ? Bt : A) +
          ((o ? bn : bm) + h * 128 + rih) * (long)K + tk * 64 + ((kch ^ (rih & 7)) * 8);
      gload_lds16(src, &Sab[buf][o][h * 8192 + (l * 512 + tid) * 8]);
    }
  };

  f32x4 acc[8][4] = {};

  stage(0, 0, 0, 0); stage(0, 0, 0, 1);
  stage(1, 0, 0, 0); stage(1, 0, 0, 1);
  stage(1, 1, 1, 0); stage(1, 1, 1, 1);
  asm volatile("s_waitcnt vmcnt(4)" ::: "memory");
  __builtin_amdgcn_s_barrier();

  for (int it = 0; it < 8; ++it) {
    const int T = 2 * it;
    const int tkA = (T + 2 < 15) ? T + 2 : 15;
    const int tkB3 = (T + 3 < 15) ? T + 3 : 15;
#pragma unroll
    for (int half = 0; half < 2; ++half) {
      const int b = half;
      short8 bfr[4][2];
      short8 afr[2][2];
#pragma unroll
      for (int g = 0; g < 4; ++g) {
        if (g == 0) {
#pragma unroll
          for (int nj = 0; nj < 4; ++nj)
#pragma unroll
            for (int kc = 0; kc < 2; ++kc) {
              const int r = wc * 64 + nj * 16 + fr;
              bfr[nj][kc] = *(const short8*)&Sab[b][1][r * 64 + ((kc * 4 + fg) ^ (r & 7)) * 8];
            }
        }
#pragma unroll
        for (int mil = 0; mil < 2; ++mil)
#pragma unroll
          for (int kc = 0; kc < 2; ++kc) {
            const int r = wr * 128 + (2 * g + mil) * 16 + fr;
            afr[mil][kc] = *(const short8*)&Sab[b][0][r * 64 + ((kc * 4 + fg) ^ (r & 7)) * 8];
          }
        if (half == 0) {
          if (g == 0)      { stage(0, 1, T + 1, 0); stage(0, 1, T + 1, 1); }
          else if (g == 1) { stage(1, 0, tkA, 0); }
          else if (g == 2) { stage(1, 0, tkA, 1); }
        } else {
          if (g == 0)      { stage(0, 0, tkA, 0); stage(0, 0, tkA, 1); }
          else if (g == 1) { stage(1, 1, tkB3, 0); }
          else if (g == 2) { stage(1, 1, tkB3, 1); }
        }
        __builtin_amdgcn_s_barrier();
        asm volatile("s_waitcnt lgkmcnt(0)" ::: "memory");
        __builtin_amdgcn_sched_barrier(0);
        __builtin_amdgcn_s_setprio(1);
#pragma unroll
        for (int mil = 0; mil < 2; ++mil)
#pragma unroll
          for (int nj = 0; nj < 4; ++nj)
#pragma unroll
            for (int kc = 0; kc < 2; ++kc)
              acc[2 * g + mil][nj] = __builtin_amdgcn_mfma_f32_16x16x32_bf16(
                  afr[mil][kc], bfr[nj][kc], acc[2 * g + mil][nj], 0, 0, 0);
        __builtin_amdgcn_s_setprio(0);
        if (g == 3) asm volatile("s_waitcnt vmcnt(4)" ::: "memory");
        __builtin_amdgcn_s_barrier();
      }
    }
  }

  const int crow = fg * 4;
  const int ccol = fr;
#pragma unroll
  for (int nj = 0; nj < 4; ++nj) {
    const long col = bn + wc * 64 + nj * 16 + ccol;
    const float bv = bias[col];
#pragma unroll
    for (int mi = 0; mi < 8; ++mi)
#pragma unroll
      for (int r = 0; r < 4; ++r) {
        const long row = bm + wr * 128 + mi * 16 + crow + r;
        C[row * ldc + col] = f2bf(acc[mi][nj][r] + bv);
      }
  }
}

// ---------------- flash attention (v15: r13 + hoisted sum-reduce) ----------------

#define KSWZ(row) (((row) & 3) | ((((row) >> 3) & 1) << 2))
#define TRRD(d, o) asm volatile("ds_read_b64_tr_b16 %0, %1 offset:" o \
                                : "=v"(d) : "v"(vtr) : "memory")
#define LGKM(n) asm volatile("s_waitcnt lgkmcnt(" #n ")" ::: "memory")

__global__ __launch_bounds__(512, 2) void attn_fwd(
    const unsigned short* __restrict__ qkv, unsigned short* __restrict__ out) {
  __shared__ unsigned short S[6 * 4096];  // Ks = S[0..3 bufs), Vs = S[3 bufs..6 bufs)
  __shared__ float msArr[512];
  unsigned short* Ks = &S[0];
  unsigned short* Vs = &S[3 * 4096];
  const int tid = threadIdx.x;
  const int lane = tid & 63;
  const int w = tid >> 6;
  const int qh = w >> 1, kh = w & 1;  // qh 0..3

  const int xcd = blockIdx.x & 7, slot = blockIdx.x >> 3;  // slot 0..63
  const int pair = xcd * 4 + (slot >> 4);                  // 0..31
  const int qtile = slot & 15;
  const int h = pair & 15, b = pair >> 4;
  const long rowbase = (long)b * 2048;
  const int hq = h * 64;
  const int fr = lane & 15;
  const int fg = lane >> 4;
  const int fk = fg * 8;
  const int q0 = qtile * 128 + qh * 32;

  short8 qf[2][2];
#pragma unroll
  for (int qi = 0; qi < 2; qi++) {
    const long qr = rowbase + q0 + qi * 16 + fr;
    qf[qi][0] = *(const short8*)&qkv[qr * 3072 + hq + fk];
    qf[qi][1] = *(const short8*)&qkv[qr * 3072 + hq + 32 + fk];
  }

  const int kr = tid >> 3;  // 0..63
  const unsigned short* Kg0 = &qkv[(rowbase + kr) * 3072 + 1024 + hq + (((tid & 7) ^ KSWZ(kr)) * 8)];
  const int vkv = ((tid >> 1) & 3) + ((tid >> 5) & 1) * 4 + ((tid >> 3) & 3) * 8 + ((tid >> 8) & 1) * 32;
  const int vd0 = (tid & 1) * 8 + ((tid >> 6) & 3) * 16;
  const unsigned short* Vg0 = &qkv[(rowbase + vkv) * 3072 + 2048 + hq + vd0];

  auto stage = [&](int tk, int buf) {
    const long off = (long)tk * 64 * 3072;
    gload_lds16(Kg0 + off, &Ks[buf * 4096 + tid * 8]);
    gload_lds16(Vg0 + off, &Vs[buf * 4096 + tid * 8]);
  };

  f32x4 o[2][4] = {};
  float m_[2] = {-1e30f, -1e30f};
  float s_[2] = {0.f, 0.f};  // per-lane partials; reduced once after the loop

  const int krowbase = kh * 32 + (fr >> 2) * 8 + (fr & 3);  // + n*4

  stage(0, 0);
  stage(1, 1);
  asm volatile("s_waitcnt vmcnt(2)" ::: "memory");
  __builtin_amdgcn_s_barrier();

  int cur = 0;

  for (int t = 0; t < 32; t++) {
    {
      int stg = cur + 2; if (stg >= 3) stg -= 3;
      const int tk = (t + 2 < 31) ? t + 2 : 31;
      stage(tk, stg);
    }

    f32x4 sa[2][2];
    __builtin_amdgcn_s_setprio(1);
#pragma unroll
    for (int n = 0; n < 2; n++) {
      const int row = krowbase + n * 4;
      const short8 kf0 = *(const short8*)&Ks[cur * 4096 + ((row * 64 + fk) ^ (KSWZ(row) << 3))];
      const short8 kf1 = *(const short8*)&Ks[cur * 4096 + ((row * 64 + 32 + fk) ^ (KSWZ(row) << 3))];
#pragma unroll
      for (int qi = 0; qi < 2; qi++) {
        f32x4 z = {0.f, 0.f, 0.f, 0.f};
        z = __builtin_amdgcn_mfma_f32_16x16x32_bf16(kf0, qf[qi][0], z, 0, 0, 0);
        sa[qi][n] = __builtin_amdgcn_mfma_f32_16x16x32_bf16(kf1, qf[qi][1], z, 0, 0, 0);
      }
    }
    __builtin_amdgcn_s_setprio(0);

    float lmax[2];
#pragma unroll
    for (int qi = 0; qi < 2; qi++)
      lmax[qi] = fmaxf(fmaxf(fmaxf(sa[qi][0][0], sa[qi][0][1]), fmaxf(sa[qi][0][2], sa[qi][0][3])),
                       fmaxf(fmaxf(sa[qi][1][0], sa[qi][1][1]), fmaxf(sa[qi][1][2], sa[qi][1][3])));
    if (__any(fmaxf(lmax[0] - m_[0], lmax[1] - m_[1]) > 8.f)) {
#pragma unroll
      for (int qi = 0; qi < 2; qi++) {
        float mx = lmax[qi];
        mx = fmaxf(mx, __shfl_xor(mx, 16));
        mx = fmaxf(mx, __shfl_xor(mx, 32));
        const float nm = fmaxf(m_[qi], mx);
        const float fac = __builtin_amdgcn_exp2f(m_[qi] - nm);
        m_[qi] = nm;
        s_[qi] *= fac;
        float facp[4];
#pragma unroll
        for (int r = 0; r < 4; r++) facp[r] = __shfl(fac, fg * 4 + r);
#pragma unroll
        for (int dj = 0; dj < 4; dj++)
#pragma unroll
          for (int r = 0; r < 4; r++) o[qi][dj][r] *= facp[r];
      }
    }

    short8 pa[2];
#pragma unroll
    for (int qi = 0; qi < 2; qi++) {
      float p[8];
#pragma unroll
      for (int n = 0; n < 2; n++)
#pragma unroll
        for (int r = 0; r < 4; r++)
          p[n * 4 + r] = __builtin_amdgcn_exp2f(sa[qi][n][r] - m_[qi]);
      s_[qi] += ((p[0] + p[1]) + (p[2] + p[3])) + ((p[4] + p[5]) + (p[6] + p[7]));
      union { unsigned u[4]; short8 v; } pk;
      pk.u[0] = cvtpk_bf16(p[0], p[1]);
      pk.u[1] = cvtpk_bf16(p[2], p[3]);
      pk.u[2] = cvtpk_bf16(p[4], p[5]);
      pk.u[3] = cvtpk_bf16(p[6], p[7]);
      pa[qi] = pk.v;
    }

    const __attribute__((address_space(3))) unsigned short* vtr =
        (const __attribute__((address_space(3))) unsigned short*)&Vs[0] +
        cur * 4096 + kh * 2048 + lane * 4;
    short4v v0[4], v1[4];
    TRRD(v0[0], "0");    TRRD(v1[0], "512");
    TRRD(v0[1], "1024"); TRRD(v1[1], "1536");
    TRRD(v0[2], "2048"); TRRD(v1[2], "2560");
    TRRD(v0[3], "3072"); TRRD(v1[3], "3584");

    __builtin_amdgcn_s_setprio(1);
    LGKM(6); __builtin_amdgcn_sched_barrier(0);
    {
      short8 vf = __builtin_shufflevector(v0[0], v1[0], 0, 1, 2, 3, 4, 5, 6, 7);
      o[0][0] = __builtin_amdgcn_mfma_f32_16x16x32_bf16(pa[0], vf, o[0][0], 0, 0, 0);
      o[1][0] = __builtin_amdgcn_mfma_f32_16x16x32_bf16(pa[1], vf, o[1][0], 0, 0, 0);
    }
    LGKM(4); __builtin_amdgcn_sched_barrier(0);
    {
      short8 vf = __builtin_shufflevector(v0[1], v1[1], 0, 1, 2, 3, 4, 5, 6, 7);
      o[0][1] = __builtin_amdgcn_mfma_f32_16x16x32_bf16(pa[0], vf, o[0][1], 0, 0, 0);
      o[1][1] = __builtin_amdgcn_mfma_f32_16x16x32_bf16(pa[1], vf, o[1][1], 0, 0, 0);
    }
    LGKM(2); __builtin_amdgcn_sched_barrier(0);
    {
      short8 vf = __builtin_shufflevector(v0[2], v1[2], 0, 1, 2, 3, 4, 5, 6, 7);
      o[0][2] = __builtin_amdgcn_mfma_f32_16x16x32_bf16(pa[0], vf, o[0][2], 0, 0, 0);
      o[1][2] = __builtin_amdgcn_mfma_f32_16x16x32_bf16(pa[1], vf, o[1][2], 0, 0, 0);
    }
    LGKM(0); __builtin_amdgcn_sched_barrier(0);
    {
      short8 vf = __builtin_shufflevector(v0[3], v1[3], 0, 1, 2, 3, 4, 5, 6, 7);
      o[0][3] = __builtin_amdgcn_mfma_f32_16x16x32_bf16(pa[0], vf, o[0][3], 0, 0, 0);
      o[1][3] = __builtin_amdgcn_mfma_f32_16x16x32_bf16(pa[1], vf, o[1][3], 0, 0, 0);
    }
    __builtin_amdgcn_s_setprio(0);

    asm volatile("s_waitcnt vmcnt(2) lgkmcnt(0)" ::: "memory");
    __builtin_amdgcn_s_barrier();

    cur = (cur == 2) ? 0 : cur + 1;
  }

#pragma unroll
  for (int qi = 0; qi < 2; qi++) {
    s_[qi] += __shfl_xor(s_[qi], 16);
    s_[qi] += __shfl_xor(s_[qi], 32);
  }

  float* mo = (float*)&S[0];
  __syncthreads();
  if (kh == 1) {
#pragma unroll
    for (int qi = 0; qi < 2; qi++)
#pragma unroll
      for (int dj = 0; dj < 4; dj++)
#pragma unroll
        for (int r = 0; r < 4; r++)
          mo[(qh * 32 + qi * 16 + dj * 4 + r) * 64 + lane] = o[qi][dj][r];
  }
  if (fg == 0) {
#pragma unroll
    for (int qi = 0; qi < 2; qi++) {
      msArr[(((kh * 4 + qh) * 2 + qi) * 2 + 0) * 16 + fr] = m_[qi];
      msArr[(((kh * 4 + qh) * 2 + qi) * 2 + 1) * 16 + fr] = s_[qi];
    }
  }
  __syncthreads();
  if (kh == 0) {
#pragma unroll
    for (int qi = 0; qi < 2; qi++) {
      float f0[4], f1[4], rs[4];
#pragma unroll
      for (int r = 0; r < 4; r++) {
        const int qp = fg * 4 + r;
        const float m0 = msArr[(((0 * 4 + qh) * 2 + qi) * 2 + 0) * 16 + qp];
        const float s0 = msArr[(((0 * 4 + qh) * 2 + qi) * 2 + 1) * 16 + qp];
        const float m1 = msArr[(((1 * 4 + qh) * 2 + qi) * 2 + 0) * 16 + qp];
        const float s1 = msArr[(((1 * 4 + qh) * 2 + qi) * 2 + 1) * 16 + qp];
        const float mstar = fmaxf(m0, m1);
        f0[r] = __builtin_amdgcn_exp2f(m0 - mstar);
        f1[r] = __builtin_amdgcn_exp2f(m1 - mstar);
        rs[r] = __builtin_amdgcn_rcpf(s0 * f0[r] + s1 * f1[r]);
      }
#pragma unroll
      for (int dj = 0; dj < 4; dj++)
#pragma unroll
        for (int r = 0; r < 4; r++) {
          const float o1 = mo[(qh * 32 + qi * 16 + dj * 4 + r) * 64 + lane];
          const float val = (o[qi][dj][r] * f0[r] + o1 * f1[r]) * rs[r];
          const long row = rowbase + q0 + qi * 16 + fg * 4 + r;
          out[row * 1024 + hq + dj * 16 + fr] = f2bf(val);
        }
    }
  }
}

// ---------------- host ----------------

extern "C" void kernel_launch(void* const* d_in, const int* in_sizes, int n_in,
                              void* d_out, int out_size, void* d_ws, size_t ws_size,
                              hipStream_t stream) {
  const float* x  = (const float*)d_in[0];
  const float* wq = (const float*)d_in[1];
  const float* bq = (const float*)d_in[2];
  const float* wk = (const float*)d_in[3];
  const float* bk = (const float*)d_in[4];
  const float* wv = (const float*)d_in[5];
  const float* bv = (const float*)d_in[6];
  const float* wo = (const float*)d_in[7];
  const float* bo = (const float*)d_in[8];

  char* ws = (char*)d_ws;
  unsigned short* xb    = (unsigned short*)(ws);                       // 8 MB  [4096][1024]
  unsigned short* wqkvT = (unsigned short*)(ws + (8ull  << 20));       // 6 MB  [3072][1024]
  unsigned short* woT   = (unsigned short*)(ws + (14ull << 20));       // 2 MB  [1024][1024]
  float*          bqkv  = (float*)         (ws + (16ull << 20));       // 12 KB [3072]
  unsigned short* qkv   = (unsigned short*)(ws + (17ull << 20));       // 24 MB [4096][3072]
  unsigned short* attn  = (unsigned short*)(ws + (41ull << 20));       // 8 MB  [4096][1024]

  prep<<<8204, 256, 0, stream>>>(x, wq, wk, wv, wo, bq, bk, bv, xb, wqkvT, woT, bqkv);

  gemm256<<<dim3(16, 12), 512, 0, stream>>>(xb, wqkvT, bqkv, qkv, 3072);

  attn_fwd<<<512, 512, 0, stream>>>(qkv, attn);

  gemm_bt64b<<<dim3(64, 16), 256, 0, stream>>>(attn, woT, bo, (float*)d_out, 1024, 1024);
}